// Round 1
// 704.452 us; speedup vs baseline: 1.0899x; 1.0899x over previous
//
#include <hip/hip_runtime.h>
#include <hip/hip_bf16.h>

// B=2,H=16,S=2048,D=64 fp32 attention returning (output, attention).
// v2: swapped-operand MFMA (lane holds 4 CONSECUTIVE keys of one q-row) ->
//     float4 nontemporal attention/O stores, b64 P staging, scalar lsum;
//     prepass converts K (bf16) and V^T (bf16) into d_ws so main-loop staging
//     is pure b128 copy (no f2bf VALU, half the read bytes); Q pre-scaled by
//     log2e/32 so softmax exp is a single v_exp_f32.

#define S_LEN 2048
#define D_DIM 64
#define BM 64
#define BN 64
#define NT (S_LEN / BN)   // 32 key tiles
#define LDP 72            // padded LDS row stride in bf16 elems (144 B)
#define BH_N 32

typedef __attribute__((ext_vector_type(8))) short bf16x8;
typedef __attribute__((ext_vector_type(4))) float f32x4;

__device__ __forceinline__ unsigned pack_bf16(float a, float b) {
    union { __hip_bfloat162 h; unsigned u; } cv;
    cv.h = __float22bfloat162_rn(make_float2(a, b));   // v_cvt_pk_bf16_f32
    return cv.u;
}
__device__ __forceinline__ unsigned short bf1(float x) {
    union { __hip_bfloat16 h; unsigned short u; } cv;
    cv.h = __float2bfloat16(x);
    return cv.u;
}

// ---- prepass: K fp32 -> bf16, same layout [bh][key][d] ----
__global__ __launch_bounds__(256)
void conv_k(const float* __restrict__ Kg, unsigned short* __restrict__ Kw) {
    size_t i = (size_t)(blockIdx.x * 256 + threadIdx.x) * 8;
    const float4 v0 = *(const float4*)(Kg + i);
    const float4 v1 = *(const float4*)(Kg + i + 4);
    uint4 o;
    o.x = pack_bf16(v0.x, v0.y);
    o.y = pack_bf16(v0.z, v0.w);
    o.z = pack_bf16(v1.x, v1.y);
    o.w = pack_bf16(v1.z, v1.w);
    *(uint4*)(Kw + i) = o;
}

// ---- prepass: V fp32 [bh][key][d] -> bf16 transposed [bh][d][key] ----
__global__ __launch_bounds__(256)
void conv_vt(const float* __restrict__ Vg, unsigned short* __restrict__ Vtw) {
    const int bh = blockIdx.y;
    const int d  = threadIdx.x & 63;
    const int kq = threadIdx.x >> 6;
    const int key0 = blockIdx.x * 32 + kq * 8;
    const float* Vb = Vg + ((size_t)bh * S_LEN + key0) * D_DIM + d;
    float f[8];
    #pragma unroll
    for (int i = 0; i < 8; ++i) f[i] = Vb[i * D_DIM];   // coalesced across d
    uint4 o;
    o.x = pack_bf16(f[0], f[1]);
    o.y = pack_bf16(f[2], f[3]);
    o.z = pack_bf16(f[4], f[5]);
    o.w = pack_bf16(f[6], f[7]);
    *(uint4*)(Vtw + ((size_t)bh * D_DIM + d) * S_LEN + key0) = o;
}

// PRE=1: K/V^T staged from pre-converted bf16 workspace. PRE=0: convert in-kernel.
template <int PRE>
__global__ __launch_bounds__(256, 4)
void attn_kernel(const float* __restrict__ Qg, const float* __restrict__ Kg,
                 const float* __restrict__ Vg, const int* __restrict__ Mg,
                 const unsigned short* __restrict__ Kw,
                 const unsigned short* __restrict__ Vtw,
                 float* __restrict__ Og, float* __restrict__ Ag) {
    __shared__ unsigned short Ks[BN * LDP];
    __shared__ unsigned short Ps[BM * LDP];
    __shared__ unsigned short QV[D_DIM * LDP];   // Q tile first, then V^T tile
    __shared__ int maskS[BN];

    const int tid  = threadIdx.x;
    const int w    = tid >> 6;
    const int lane = tid & 63;
    const int l15  = lane & 15;
    const int quad = lane >> 4;

    const int qt = blockIdx.x;
    const int bh = blockIdx.y;
    const int b  = bh >> 4;
    const int q0 = qt * BM;
    const int qrow = w * 16 + l15;     // this lane's q row within the tile

    const float* Qb = Qg + ((size_t)bh * S_LEN + q0) * D_DIM;
    const int*   Mb = Mg + (size_t)b * S_LEN;
    float* Ob = Og + ((size_t)bh * S_LEN + q0) * D_DIM;
    float* Ab = Ag + ((size_t)bh * S_LEN + q0) * (size_t)S_LEN;

    // ---- stage Q scaled by log2(e)/32 (folds temperature AND exp->exp2) ----
    {
        const float sc = 0.04508422f;  // log2(e)/32
        #pragma unroll
        for (int i = 0; i < 4; ++i) {
            int f = tid + i * 256;
            int row = f >> 4, c4 = f & 15;
            const float4 v = *(const float4*)(Qb + row * D_DIM + c4 * 4);
            *(uint2*)(&QV[row * LDP + c4 * 4]) =
                make_uint2(pack_bf16(v.x * sc, v.y * sc), pack_bf16(v.z * sc, v.w * sc));
        }
    }
    __syncthreads();

    // Q fragment, reused every tile in both passes (B-operand of swapped MFMA).
    bf16x8 aq[2];
    #pragma unroll
    for (int ks = 0; ks < 2; ++ks)
        aq[ks] = *(const bf16x8*)(&QV[qrow * LDP + ks * 32 + quad * 8]);
    // pass-1 barriers order these reads before pass-2 overwrites QV with V^T.

    auto stage_k = [&](int key0) {
        if constexpr (PRE) {
            const unsigned short* Kt = Kw + (size_t)bh * S_LEN * D_DIM + (size_t)key0 * D_DIM;
            #pragma unroll
            for (int i = 0; i < 2; ++i) {
                int idx = tid + i * 256;            // 512 chunks of 8 bf16
                int row = idx >> 3, c = idx & 7;
                uint4 vv = *(const uint4*)(Kt + row * D_DIM + c * 8);
                *(uint4*)(&Ks[row * LDP + c * 8]) = vv;
            }
        } else {
            const float* Kb = Kg + ((size_t)bh * S_LEN + key0) * D_DIM;
            #pragma unroll
            for (int i = 0; i < 4; ++i) {
                int f = tid + i * 256;
                int row = f >> 4, c4 = f & 15;
                const float4 v = *(const float4*)(Kb + row * D_DIM + c4 * 4);
                *(uint2*)(&Ks[row * LDP + c4 * 4]) =
                    make_uint2(pack_bf16(v.x, v.y), pack_bf16(v.z, v.w));
            }
        }
    };

    // ================= Pass 1: row sums of exp2(s) =================
    // Swapped MFMA: acc = K_frag * Q_frag -> D[row=key=quad*4+r][col=q=l15].
    float lsum = 0.f;

    for (int kt = 0; kt < NT; ++kt) {
        const int key0 = kt * BN;
        stage_k(key0);
        if (tid < BN) maskS[tid] = Mb[key0 + tid];
        __syncthreads();

        #pragma unroll
        for (int cb = 0; cb < 4; ++cb) {
            f32x4 acc = {0.f, 0.f, 0.f, 0.f};
            #pragma unroll
            for (int ks = 0; ks < 2; ++ks) {
                bf16x8 bk = *(const bf16x8*)(&Ks[(cb * 16 + l15) * LDP + ks * 32 + quad * 8]);
                acc = __builtin_amdgcn_mfma_f32_16x16x32_bf16(bk, aq[ks], acc, 0, 0, 0);
            }
            const int4 m4 = *(const int4*)(&maskS[cb * 16 + quad * 4]);
            float e0 = m4.x ? __builtin_exp2f(acc[0]) : 0.f;
            float e1 = m4.y ? __builtin_exp2f(acc[1]) : 0.f;
            float e2 = m4.z ? __builtin_exp2f(acc[2]) : 0.f;
            float e3 = m4.w ? __builtin_exp2f(acc[3]) : 0.f;
            lsum += (e0 + e1) + (e2 + e3);
        }
        __syncthreads();
    }

    // quads hold disjoint key subsets of the SAME q row -> 2-shuffle reduce
    lsum += __shfl_xor(lsum, 16);
    lsum += __shfl_xor(lsum, 32);
    const float linv = 1.0f / lsum;

    // ================= Pass 2: write P (float4 nt), O += P V =================
    f32x4 oacc[4];
    #pragma unroll
    for (int db = 0; db < 4; ++db) oacc[db] = (f32x4){0.f, 0.f, 0.f, 0.f};

    for (int kt = 0; kt < NT; ++kt) {
        const int key0 = kt * BN;
        stage_k(key0);
        if constexpr (PRE) {
            const unsigned short* Vt = Vtw + (size_t)bh * D_DIM * S_LEN + key0;
            #pragma unroll
            for (int i = 0; i < 2; ++i) {
                int idx = tid + i * 256;
                int d = idx >> 3, c = idx & 7;
                uint4 vv = *(const uint4*)(Vt + (size_t)d * S_LEN + c * 8);
                *(uint4*)(&QV[d * LDP + c * 8]) = vv;
            }
        } else {
            int key = tid & 63, g = tid >> 6;
            #pragma unroll
            for (int i = 0; i < 4; ++i) {
                int d0 = (g * 4 + i) * 4;
                const float4 v = *(const float4*)(Vg + ((size_t)bh * S_LEN + key0 + key) * D_DIM + d0);
                QV[(d0 + 0) * LDP + key] = bf1(v.x);
                QV[(d0 + 1) * LDP + key] = bf1(v.y);
                QV[(d0 + 2) * LDP + key] = bf1(v.z);
                QV[(d0 + 3) * LDP + key] = bf1(v.w);
            }
        }
        if (tid < BN) maskS[tid] = Mb[key0 + tid];
        __syncthreads();

        #pragma unroll
        for (int cb = 0; cb < 4; ++cb) {
            f32x4 acc = {0.f, 0.f, 0.f, 0.f};
            #pragma unroll
            for (int ks = 0; ks < 2; ++ks) {
                bf16x8 bk = *(const bf16x8*)(&Ks[(cb * 16 + l15) * LDP + ks * 32 + quad * 8]);
                acc = __builtin_amdgcn_mfma_f32_16x16x32_bf16(bk, aq[ks], acc, 0, 0, 0);
            }
            const int4 m4 = *(const int4*)(&maskS[cb * 16 + quad * 4]);
            f32x4 p;
            p[0] = (m4.x ? __builtin_exp2f(acc[0]) : 0.f) * linv;
            p[1] = (m4.y ? __builtin_exp2f(acc[1]) : 0.f) * linv;
            p[2] = (m4.z ? __builtin_exp2f(acc[2]) : 0.f) * linv;
            p[3] = (m4.w ? __builtin_exp2f(acc[3]) : 0.f) * linv;
            // 4 consecutive keys of row qrow -> one 16B nontemporal store
            __builtin_nontemporal_store(
                p, (f32x4*)(Ab + (size_t)qrow * S_LEN + key0 + cb * 16 + quad * 4));
            *(uint2*)(&Ps[qrow * LDP + cb * 16 + quad * 4]) =
                make_uint2(pack_bf16(p[0], p[1]), pack_bf16(p[2], p[3]));
        }

        // PV (swapped: A=V^T frag, B=P frag) -> lane holds 4 consecutive d of row qrow.
        // Ps rows for wave w written only by wave w -> same-wave RAW, no barrier.
        #pragma unroll
        for (int ks2 = 0; ks2 < 2; ++ks2) {
            bf16x8 ap = *(const bf16x8*)(&Ps[qrow * LDP + ks2 * 32 + quad * 8]);
            #pragma unroll
            for (int db = 0; db < 4; ++db) {
                bf16x8 bv = *(const bf16x8*)(&QV[(db * 16 + l15) * LDP + ks2 * 32 + quad * 8]);
                oacc[db] = __builtin_amdgcn_mfma_f32_16x16x32_bf16(bv, ap, oacc[db], 0, 0, 0);
            }
        }
        __syncthreads();
    }

    // write O: lane holds d = db*16 + quad*4 + r for row qrow -> float4 stores
    #pragma unroll
    for (int db = 0; db < 4; ++db) {
        f32x4 o4 = oacc[db];
        __builtin_nontemporal_store(
            o4, (f32x4*)(Ob + (size_t)qrow * D_DIM + db * 16 + quad * 4));
    }
}

extern "C" void kernel_launch(void* const* d_in, const int* in_sizes, int n_in,
                              void* d_out, int out_size, void* d_ws, size_t ws_size,
                              hipStream_t stream) {
    const float* q = (const float*)d_in[0];
    const float* k = (const float*)d_in[1];
    const float* v = (const float*)d_in[2];
    const int* mask = (const int*)d_in[3];
    float* out = (float*)d_out;                         // [B,H,S,D]
    float* attn = out + (size_t)2 * 16 * 2048 * 64;     // [B,H,S,S]

    const size_t kw_elems = (size_t)BH_N * S_LEN * D_DIM;        // 4.19M bf16
    const size_t need = 2 * kw_elems * sizeof(unsigned short);   // 16.8 MB
    dim3 block(256);
    dim3 grid(S_LEN / BM, BH_N);

    if (d_ws && ws_size >= need) {
        unsigned short* Kw  = (unsigned short*)d_ws;
        unsigned short* Vtw = Kw + kw_elems;
        conv_k<<<dim3((unsigned)(kw_elems / 8 / 256)), block, 0, stream>>>(k, Kw);
        conv_vt<<<dim3(S_LEN / 32, BH_N), block, 0, stream>>>(v, Vtw);
        attn_kernel<1><<<grid, block, 0, stream>>>(q, k, v, mask, Kw, Vtw, out, attn);
    } else {
        attn_kernel<0><<<grid, block, 0, stream>>>(q, k, v, mask, nullptr, nullptr, out, attn);
    }
}

// Round 2
// 644.578 us; speedup vs baseline: 1.1911x; 1.0929x over previous
//
#include <hip/hip_runtime.h>
#include <hip/hip_bf16.h>

// B=2,H=16,S=2048,D=64 fp32 attention returning (output, attention).
// v3: P-tile staged fp32 in LDS, then cooperatively stored with 256B-contiguous
//     segments per row (was 64B scattered) -> full 128B-line write efficiency on
//     the 537MB attention stream. PV fragments packed from the fp32 LDS tile
//     (cvt_pk, same RNE rounding) so the bf16 Ps buffer is gone; LDS stays 36KB
//     (4 blocks/CU). Prepass K->bf16 and V->bf16^T in d_ws as in v2.

#define S_LEN 2048
#define D_DIM 64
#define BM 64
#define BN 64
#define NT (S_LEN / BN)   // 32 key tiles
#define LDP 72            // padded LDS row stride in bf16 elems (144 B)
#define LDF 68            // padded LDS row stride for fp32 P tile (272 B)
#define BH_N 32

typedef __attribute__((ext_vector_type(8))) short bf16x8;
typedef __attribute__((ext_vector_type(4))) float f32x4;

__device__ __forceinline__ unsigned pack_bf16(float a, float b) {
    union { __hip_bfloat162 h; unsigned u; } cv;
    cv.h = __float22bfloat162_rn(make_float2(a, b));   // v_cvt_pk_bf16_f32
    return cv.u;
}
__device__ __forceinline__ unsigned short bf1(float x) {
    union { __hip_bfloat16 h; unsigned short u; } cv;
    cv.h = __float2bfloat16(x);
    return cv.u;
}

// ---- prepass: K fp32 -> bf16, same layout [bh][key][d] ----
__global__ __launch_bounds__(256)
void conv_k(const float* __restrict__ Kg, unsigned short* __restrict__ Kw) {
    size_t i = (size_t)(blockIdx.x * 256 + threadIdx.x) * 8;
    const float4 v0 = *(const float4*)(Kg + i);
    const float4 v1 = *(const float4*)(Kg + i + 4);
    uint4 o;
    o.x = pack_bf16(v0.x, v0.y);
    o.y = pack_bf16(v0.z, v0.w);
    o.z = pack_bf16(v1.x, v1.y);
    o.w = pack_bf16(v1.z, v1.w);
    *(uint4*)(Kw + i) = o;
}

// ---- prepass: V fp32 [bh][key][d] -> bf16 transposed [bh][d][key] ----
__global__ __launch_bounds__(256)
void conv_vt(const float* __restrict__ Vg, unsigned short* __restrict__ Vtw) {
    const int bh = blockIdx.y;
    const int d  = threadIdx.x & 63;
    const int kq = threadIdx.x >> 6;
    const int key0 = blockIdx.x * 32 + kq * 8;
    const float* Vb = Vg + ((size_t)bh * S_LEN + key0) * D_DIM + d;
    float f[8];
    #pragma unroll
    for (int i = 0; i < 8; ++i) f[i] = Vb[i * D_DIM];   // coalesced across d
    uint4 o;
    o.x = pack_bf16(f[0], f[1]);
    o.y = pack_bf16(f[2], f[3]);
    o.z = pack_bf16(f[4], f[5]);
    o.w = pack_bf16(f[6], f[7]);
    *(uint4*)(Vtw + ((size_t)bh * D_DIM + d) * S_LEN + key0) = o;
}

// PRE=1: K/V^T staged from pre-converted bf16 workspace. PRE=0: convert in-kernel.
template <int PRE>
__global__ __launch_bounds__(256, 4)
void attn_kernel(const float* __restrict__ Qg, const float* __restrict__ Kg,
                 const float* __restrict__ Vg, const int* __restrict__ Mg,
                 const unsigned short* __restrict__ Kw,
                 const unsigned short* __restrict__ Vtw,
                 float* __restrict__ Og, float* __restrict__ Ag) {
    __shared__ unsigned short Ks[BN * LDP];      // 9216 B
    __shared__ unsigned short QV[D_DIM * LDP];   // 9216 B: Q tile, then V^T tile
    __shared__ float Pf[BM * LDF];               // 17408 B: fp32 P tile
    __shared__ int maskS[BN];

    const int tid  = threadIdx.x;
    const int w    = tid >> 6;
    const int lane = tid & 63;
    const int l15  = lane & 15;
    const int quad = lane >> 4;

    const int qt = blockIdx.x;
    const int bh = blockIdx.y;
    const int b  = bh >> 4;
    const int q0 = qt * BM;
    const int qrow = w * 16 + l15;     // this lane's q row within the tile

    const float* Qb = Qg + ((size_t)bh * S_LEN + q0) * D_DIM;
    const int*   Mb = Mg + (size_t)b * S_LEN;
    float* Ob = Og + ((size_t)bh * S_LEN + q0) * D_DIM;
    float* Ab = Ag + ((size_t)bh * S_LEN + q0) * (size_t)S_LEN;

    // ---- stage Q scaled by log2(e)/32 (folds temperature AND exp->exp2) ----
    {
        const float sc = 0.04508422f;  // log2(e)/32
        #pragma unroll
        for (int i = 0; i < 4; ++i) {
            int f = tid + i * 256;
            int row = f >> 4, c4 = f & 15;
            const float4 v = *(const float4*)(Qb + row * D_DIM + c4 * 4);
            *(uint2*)(&QV[row * LDP + c4 * 4]) =
                make_uint2(pack_bf16(v.x * sc, v.y * sc), pack_bf16(v.z * sc, v.w * sc));
        }
    }
    __syncthreads();

    // Q fragment, reused every tile in both passes (B-operand of swapped MFMA).
    bf16x8 aq[2];
    #pragma unroll
    for (int ks = 0; ks < 2; ++ks)
        aq[ks] = *(const bf16x8*)(&QV[qrow * LDP + ks * 32 + quad * 8]);
    // pass-1 barriers order these reads before pass-2 overwrites QV with V^T.

    auto stage_k = [&](int key0) {
        if constexpr (PRE) {
            const unsigned short* Kt = Kw + (size_t)bh * S_LEN * D_DIM + (size_t)key0 * D_DIM;
            #pragma unroll
            for (int i = 0; i < 2; ++i) {
                int idx = tid + i * 256;            // 512 chunks of 8 bf16
                int row = idx >> 3, c = idx & 7;
                uint4 vv = *(const uint4*)(Kt + row * D_DIM + c * 8);
                *(uint4*)(&Ks[row * LDP + c * 8]) = vv;
            }
        } else {
            const float* Kb = Kg + ((size_t)bh * S_LEN + key0) * D_DIM;
            #pragma unroll
            for (int i = 0; i < 4; ++i) {
                int f = tid + i * 256;
                int row = f >> 4, c4 = f & 15;
                const float4 v = *(const float4*)(Kb + row * D_DIM + c4 * 4);
                *(uint2*)(&Ks[row * LDP + c4 * 4]) =
                    make_uint2(pack_bf16(v.x, v.y), pack_bf16(v.z, v.w));
            }
        }
    };

    // ================= Pass 1: row sums of exp2(s) =================
    // Swapped MFMA: acc = K_frag * Q_frag -> D[row=key=quad*4+r][col=q=l15].
    float lsum = 0.f;

    for (int kt = 0; kt < NT; ++kt) {
        const int key0 = kt * BN;
        stage_k(key0);
        if (tid < BN) maskS[tid] = Mb[key0 + tid];
        __syncthreads();

        #pragma unroll
        for (int cb = 0; cb < 4; ++cb) {
            f32x4 acc = {0.f, 0.f, 0.f, 0.f};
            #pragma unroll
            for (int ks = 0; ks < 2; ++ks) {
                bf16x8 bk = *(const bf16x8*)(&Ks[(cb * 16 + l15) * LDP + ks * 32 + quad * 8]);
                acc = __builtin_amdgcn_mfma_f32_16x16x32_bf16(bk, aq[ks], acc, 0, 0, 0);
            }
            const int4 m4 = *(const int4*)(&maskS[cb * 16 + quad * 4]);
            float e0 = m4.x ? __builtin_exp2f(acc[0]) : 0.f;
            float e1 = m4.y ? __builtin_exp2f(acc[1]) : 0.f;
            float e2 = m4.z ? __builtin_exp2f(acc[2]) : 0.f;
            float e3 = m4.w ? __builtin_exp2f(acc[3]) : 0.f;
            lsum += (e0 + e1) + (e2 + e3);
        }
        __syncthreads();
    }

    // quads hold disjoint key subsets of the SAME q row -> 2-shuffle reduce
    lsum += __shfl_xor(lsum, 16);
    lsum += __shfl_xor(lsum, 32);
    const float linv = 1.0f / lsum;

    // ================= Pass 2: P -> LDS fp32, O += P V, coalesced P store ====
    f32x4 oacc[4];
    #pragma unroll
    for (int db = 0; db < 4; ++db) oacc[db] = (f32x4){0.f, 0.f, 0.f, 0.f};

    for (int kt = 0; kt < NT; ++kt) {
        const int key0 = kt * BN;
        stage_k(key0);
        if constexpr (PRE) {
            const unsigned short* Vt = Vtw + (size_t)bh * D_DIM * S_LEN + key0;
            #pragma unroll
            for (int i = 0; i < 2; ++i) {
                int idx = tid + i * 256;
                int d = idx >> 3, c = idx & 7;
                uint4 vv = *(const uint4*)(Vt + (size_t)d * S_LEN + c * 8);
                *(uint4*)(&QV[d * LDP + c * 8]) = vv;
            }
        } else {
            int key = tid & 63, g = tid >> 6;
            #pragma unroll
            for (int i = 0; i < 4; ++i) {
                int d0 = (g * 4 + i) * 4;
                const float4 v = *(const float4*)(Vg + ((size_t)bh * S_LEN + key0 + key) * D_DIM + d0);
                QV[(d0 + 0) * LDP + key] = bf1(v.x);
                QV[(d0 + 1) * LDP + key] = bf1(v.y);
                QV[(d0 + 2) * LDP + key] = bf1(v.z);
                QV[(d0 + 3) * LDP + key] = bf1(v.w);
            }
        }
        if (tid < BN) maskS[tid] = Mb[key0 + tid];
        // Barrier also orders the previous tile's cooperative Pf reads before
        // this tile's Pf writes in the cb loop below.
        __syncthreads();

        #pragma unroll
        for (int cb = 0; cb < 4; ++cb) {
            f32x4 acc = {0.f, 0.f, 0.f, 0.f};
            #pragma unroll
            for (int ks = 0; ks < 2; ++ks) {
                bf16x8 bk = *(const bf16x8*)(&Ks[(cb * 16 + l15) * LDP + ks * 32 + quad * 8]);
                acc = __builtin_amdgcn_mfma_f32_16x16x32_bf16(bk, aq[ks], acc, 0, 0, 0);
            }
            const int4 m4 = *(const int4*)(&maskS[cb * 16 + quad * 4]);
            f32x4 p;
            p[0] = (m4.x ? __builtin_exp2f(acc[0]) : 0.f) * linv;
            p[1] = (m4.y ? __builtin_exp2f(acc[1]) : 0.f) * linv;
            p[2] = (m4.z ? __builtin_exp2f(acc[2]) : 0.f) * linv;
            p[3] = (m4.w ? __builtin_exp2f(acc[3]) : 0.f) * linv;
            *(f32x4*)(&Pf[qrow * LDF + cb * 16 + quad * 4]) = p;
        }

        // PV (swapped: A=V^T frag, B=P frag built from fp32 Pf rows via cvt_pk).
        // Pf rows for wave w written only by wave w -> same-wave RAW, no barrier.
        #pragma unroll
        for (int ks2 = 0; ks2 < 2; ++ks2) {
            const float* pr = &Pf[qrow * LDF + ks2 * 32 + quad * 8];
            f32x4 pa = *(const f32x4*)(pr);
            f32x4 pb = *(const f32x4*)(pr + 4);
            union { bf16x8 v; uint4 u; } ap;
            ap.u.x = pack_bf16(pa[0], pa[1]);
            ap.u.y = pack_bf16(pa[2], pa[3]);
            ap.u.z = pack_bf16(pb[0], pb[1]);
            ap.u.w = pack_bf16(pb[2], pb[3]);
            #pragma unroll
            for (int db = 0; db < 4; ++db) {
                bf16x8 bv = *(const bf16x8*)(&QV[(db * 16 + l15) * LDP + ks2 * 32 + quad * 8]);
                oacc[db] = __builtin_amdgcn_mfma_f32_16x16x32_bf16(bv, ap.v, oacc[db], 0, 0, 0);
            }
        }
        __syncthreads();   // Pf fully written; also K/QV reads done before restage

        // Cooperative coalesced P store: each wave instr = 4 rows x 256B segments.
        // Overlaps with next iteration's staging loads (no barrier in between).
        #pragma unroll
        for (int i = 0; i < 4; ++i) {
            int idx = tid + i * 256;           // 0..1023 float4 chunks
            int row = idx >> 4, c4 = idx & 15;
            f32x4 t = *(const f32x4*)(&Pf[row * LDF + c4 * 4]);
            __builtin_nontemporal_store(
                t, (f32x4*)(Ab + (size_t)row * S_LEN + key0 + c4 * 4));
        }
    }

    // write O: lane holds d = db*16 + quad*4 + r for row qrow -> float4 stores
    #pragma unroll
    for (int db = 0; db < 4; ++db) {
        f32x4 o4 = oacc[db];
        __builtin_nontemporal_store(
            o4, (f32x4*)(Ob + (size_t)qrow * D_DIM + db * 16 + quad * 4));
    }
}

extern "C" void kernel_launch(void* const* d_in, const int* in_sizes, int n_in,
                              void* d_out, int out_size, void* d_ws, size_t ws_size,
                              hipStream_t stream) {
    const float* q = (const float*)d_in[0];
    const float* k = (const float*)d_in[1];
    const float* v = (const float*)d_in[2];
    const int* mask = (const int*)d_in[3];
    float* out = (float*)d_out;                         // [B,H,S,D]
    float* attn = out + (size_t)2 * 16 * 2048 * 64;     // [B,H,S,S]

    const size_t kw_elems = (size_t)BH_N * S_LEN * D_DIM;        // 4.19M bf16
    const size_t need = 2 * kw_elems * sizeof(unsigned short);   // 16.8 MB
    dim3 block(256);
    dim3 grid(S_LEN / BM, BH_N);

    if (d_ws && ws_size >= need) {
        unsigned short* Kw  = (unsigned short*)d_ws;
        unsigned short* Vtw = Kw + kw_elems;
        conv_k<<<dim3((unsigned)(kw_elems / 8 / 256)), block, 0, stream>>>(k, Kw);
        conv_vt<<<dim3(S_LEN / 32, BH_N), block, 0, stream>>>(v, Vtw);
        attn_kernel<1><<<grid, block, 0, stream>>>(q, k, v, mask, Kw, Vtw, out, attn);
    } else {
        attn_kernel<0><<<grid, block, 0, stream>>>(q, k, v, mask, nullptr, nullptr, out, attn);
    }
}